// Round 13
// baseline (229.115 us; speedup 1.0000x reference)
//
#include <hip/hip_runtime.h>
#include <math.h>

// ---------------------------------------------------------------------------
// Problem constants
// ---------------------------------------------------------------------------
#define N_SEQ   896
#define DH      3072
#define NCTX    64
#define JLEN    127
#define DC      1024
#define HEADS   8
#define DHEAD   64
#define INNER   512   // HEADS*DHEAD
#define MKV     8128  // NCTX*JLEN
#define MKVPAD  8192

typedef __bf16 bf16x8 __attribute__((ext_vector_type(8)));
typedef float  f32x4  __attribute__((ext_vector_type(4)));

// workspace float offsets
#define OFF_EDOT   0LL
#define OFF_QBF    (OFF_EDOT + N_SEQ)
#define OFF_KBF    (OFF_QBF  + (long long)N_SEQ*INNER/2)     // bf16 896x512
#define OFF_VPM    (OFF_KBF  + (long long)NCTX*128*INNER/2)  // fp32 8128x8
#define OFF_VPNULL (OFF_VPM  + (long long)MKV*8)
#define OFF_WOP    (OFF_VPNULL + 8)                          // (unused, layout kept)
#define OFF_BOP    (OFF_WOP  + INNER)
#define OFF_SBUF   (OFF_BOP  + 16)                           // fp32 64*8*896
#define OFF_ANQ    (OFF_SBUF + (long long)NCTX*HEADS*N_SEQ)  // bf16 896x3072
#define OFF_ANKV   (OFF_ANQ  + (long long)N_SEQ*DH/2)        // (unused now)
#define OFF_WQT    (OFF_ANKV + (long long)MKVPAD*DC/2)       // bf16 512x3072
#define OFF_WKT    (OFF_WQT  + (long long)INNER*DH/2)        // bf16 512x1024
#define OFF_WVPT   (OFF_WKT  + (long long)INNER*DC/2)        // bf16 16x1024
#define OFF_QSL    (OFF_WVPT + 16*1024/2)                    // fp32 8 x 896x512
#define OFF_MRS    (OFF_QSL  + (long long)8*N_SEQ*INNER)     // fp32 8128 x {m,rs}

// ---------------------------------------------------------------------------
__device__ __forceinline__ void async_copy16(const __bf16* g, __bf16* l) {
    __builtin_amdgcn_global_load_lds(
        (const __attribute__((address_space(1))) unsigned int*)g,
        (__attribute__((address_space(3))) unsigned int*)l,
        16, 0, 0);
}

// ---------------------------------------------------------------------------
// K1 prep: kv LN reduced to STATS-ONLY (normalize moved into proj k-GEMM).
//   blocks [0,8)        per-head: wop slice -> WVPT row + VPNULL
//   block  8            BOP = dot(bo, Wp)
//   block  9            misc: WVPT zero pad + null_k rows of KBF
//   blocks [10,518)     kv LN stats: 16 rows/block (4 rows/wave) -> MRS
//   blocks [518,742)    q LayerNorm + emb.Wp dot, wave-per-row, two-pass
//   blocks [742,2790)   32x32 transposes: Wq->WQT (1536), Wkv k-half->WKT (512)
// ---------------------------------------------------------------------------
#define P_KV0  10
#define P_Q0   (P_KV0 + 508)    // 518
#define P_T0   (P_Q0 + 224)     // 742
#define GRIDP  (P_T0 + 2048)    // 2790

__global__ __launch_bounds__(256)
void prep_kernel(const float* __restrict__ emb, const float* __restrict__ ctx,
                 const float* __restrict__ qg, const float* __restrict__ qb_,
                 const float* __restrict__ Wq, const float* __restrict__ Wkv,
                 const float* __restrict__ Wo, const float* __restrict__ bo,
                 const float* __restrict__ Wp,
                 const float* __restrict__ nullk, const float* __restrict__ nullv,
                 __bf16* __restrict__ ANQ, float* __restrict__ MRS,
                 __bf16* __restrict__ WQT, __bf16* __restrict__ WKT,
                 __bf16* __restrict__ WVPT, float* __restrict__ VPNULL,
                 float* __restrict__ EDOT, float* __restrict__ BOP,
                 __bf16* __restrict__ KBF)
{
    __shared__ __align__(16) float SM[3072 + 64];
    const int bid = blockIdx.x, tid = threadIdx.x;
    const int lane = tid & 63, wid = tid >> 6;

    if (bid < 8) {
        // ---- per-head: self-contained wop slice -> WVPT row + VPNULL ----
        int h = bid;
        float* wpsh = SM;              // 3072 floats
        float* wops = SM + 3072;       // 64 floats
        for (int i = tid; i < 768; i += 256)
            ((f32x4*)wpsh)[i] = ((const f32x4*)Wp)[i];
        __syncthreads();
        for (int rr = 0; rr < 16; ++rr) {
            int d = wid * 16 + rr;
            const float* worow = Wo + (long long)(h * 64 + d) * DH;
            float s = 0.f;
            #pragma unroll
            for (int c = 0; c < 12; ++c) {
                int col = c * 256 + lane * 4;
                float4 a = *(const float4*)&worow[col];
                s += a.x*wpsh[col] + a.y*wpsh[col+1] + a.z*wpsh[col+2] + a.w*wpsh[col+3];
            }
            #pragma unroll
            for (int o = 1; o < 64; o <<= 1) s += __shfl_xor(s, o);
            if (lane == 0) wops[d] = s;
        }
        __syncthreads();
        if (tid < 64) {
            float v = nullv[h * 64 + tid] * wops[tid];
            #pragma unroll
            for (int o = 1; o < 64; o <<= 1) v += __shfl_xor(v, o);
            if (tid == 0) VPNULL[h] = v;
        }
        #pragma unroll
        for (int kk = 0; kk < 4; ++kk) {
            int k = kk * 256 + tid;
            const float* src = Wkv + (long long)k * (2 * INNER) + INNER + h * 64;
            float s2 = 0.f;
            #pragma unroll
            for (int d2 = 0; d2 < 64; d2 += 4) {
                float4 a = *(const float4*)&src[d2];
                s2 += a.x*wops[d2] + a.y*wops[d2+1] + a.z*wops[d2+2] + a.w*wops[d2+3];
            }
            WVPT[h * 1024 + k] = (__bf16)s2;
        }
    } else if (bid == 8) {
        // ---- BOP = dot(bo, Wp) ----
        float* red = SM;
        float s = 0.f;
        #pragma unroll
        for (int i = 0; i < 3; ++i) {
            int k = i * 1024 + tid * 4;
            float4 a = *(const float4*)&bo[k];
            float4 w = *(const float4*)&Wp[k];
            s += a.x*w.x + a.y*w.y + a.z*w.z + a.w*w.w;
        }
        #pragma unroll
        for (int o = 1; o < 64; o <<= 1) s += __shfl_xor(s, o);
        if (lane == 0) red[wid] = s;
        __syncthreads();
        if (tid == 0) *BOP = red[0] + red[1] + red[2] + red[3];
    } else if (bid == 9) {
        // ---- misc: WVPT zero pad rows 8..15 + null_k rows of KBF ----
        for (int i = tid; i < 8 * 1024; i += 256)
            WVPT[8 * 1024 + i] = (__bf16)0.f;
        for (int i = tid; i < NCTX * INNER; i += 256) {
            int c = i >> 9, d2 = i & 511;
            KBF[(long long)(c * 128) * INNER + d2] = (__bf16)nullk[d2];
        }
    } else if (bid < P_Q0) {
        // ---- kv LN STATS: 4 rows/wave, 16 indep loads up front, no retention
        //      (accumulation order identical to the old LN -> same m,rs bits)
        int r0 = (bid - P_KV0) * 16 + wid * 4;       // 0..8124
        const float* x = ctx + (long long)r0 * DC;
        float s[4] = {0.f,0.f,0.f,0.f}, ss[4] = {0.f,0.f,0.f,0.f};
        #pragma unroll
        for (int rr = 0; rr < 4; ++rr) {
            #pragma unroll
            for (int c = 0; c < 4; ++c) {
                f32x4 v = *(const f32x4*)&x[(long long)rr * DC + c * 256 + lane * 4];
                s[rr]  += v[0] + v[1] + v[2] + v[3];
                ss[rr] += v[0]*v[0] + v[1]*v[1] + v[2]*v[2] + v[3]*v[3];
            }
        }
        #pragma unroll
        for (int o = 1; o < 64; o <<= 1) {
            #pragma unroll
            for (int rr = 0; rr < 4; ++rr) {
                s[rr] += __shfl_xor(s[rr], o); ss[rr] += __shfl_xor(ss[rr], o);
            }
        }
        if (lane == 0) {
            #pragma unroll
            for (int rr = 0; rr < 4; ++rr) {
                float m  = s[rr] * (1.f / DC);
                float rs = rsqrtf(ss[rr] * (1.f / DC) - m * m + 1e-5f);
                MRS[(long long)(r0 + rr) * 2]     = m;
                MRS[(long long)(r0 + rr) * 2 + 1] = rs;
            }
        }
    } else if (bid < P_T0) {
        // ---- q LN: one wave per row, two-pass (emb re-read from L2) ----
        int r = (bid - P_Q0) * 4 + wid;              // 0..895
        const float* x = emb + (long long)r * DH;
        float s = 0.f, ss = 0.f, dp = 0.f;
        #pragma unroll
        for (int c = 0; c < 12; ++c) {
            int col = c * 256 + lane * 4;
            float4 a = *(const float4*)&x[col];
            float4 w = *(const float4*)&Wp[col];
            s  += a.x + a.y + a.z + a.w;
            ss += a.x*a.x + a.y*a.y + a.z*a.z + a.w*a.w;
            dp += a.x*w.x + a.y*w.y + a.z*w.z + a.w*w.w;
        }
        #pragma unroll
        for (int o = 1; o < 64; o <<= 1) {
            s += __shfl_xor(s, o); ss += __shfl_xor(ss, o); dp += __shfl_xor(dp, o);
        }
        float m  = s * (1.f / DH);
        float rs = rsqrtf(ss * (1.f / DH) - m * m + 1e-5f);
        __bf16* op = ANQ + (long long)r * DH;
        #pragma unroll
        for (int c = 0; c < 12; ++c) {
            int col = c * 256 + lane * 4;
            float4 a  = *(const float4*)&x[col];
            float4 g4 = *(const float4*)&qg[col];
            float4 b4 = *(const float4*)&qb_[col];
            __bf16 ov[4];
            ov[0] = (__bf16)((a.x - m) * rs * g4.x + b4.x);
            ov[1] = (__bf16)((a.y - m) * rs * g4.y + b4.y);
            ov[2] = (__bf16)((a.z - m) * rs * g4.z + b4.z);
            ov[3] = (__bf16)((a.w - m) * rs * g4.w + b4.w);
            *(ushort4*)&op[col] = *(ushort4*)ov;
        }
        if (lane == 0) EDOT[r] = dp;
    } else {
        // ---- 32x32 transpose tiles ----
        int t = bid - P_T0;
        float (*tT)[33] = (float(*)[33])SM;
        const float* src; __bf16* dst; int srcS, dstS, rb, cb;
        if (t < 1536) {
            rb = (t >> 4) * 32; cb = (t & 15) * 32;
            src = Wq; srcS = INNER; dst = WQT; dstS = DH;
        } else {
            int bi = t - 1536;
            rb = (bi >> 4) * 32; cb = (bi & 15) * 32;
            src = Wkv; srcS = 2 * INNER; dst = WKT; dstS = DC;
        }
        int tx = tid & 31, ty = tid >> 5;
        #pragma unroll
        for (int i = 0; i < 32; i += 8)
            tT[ty + i][tx] = src[(long long)(rb + ty + i) * srcS + cb + tx];
        __syncthreads();
        #pragma unroll
        for (int i = 0; i < 32; i += 8)
            dst[(long long)(cb + ty + i) * dstS + rb + tx] = (__bf16)tT[tx][ty + i];
    }
}

// ---------------------------------------------------------------------------
// K2: merged projection GEMM. q-blocks unchanged (global_load_lds ANQ/WQT).
// k-blocks: A-tile = LN(ctx) computed IN-STAGING (reg load f32 -> normalize
// -> bf16 -> ds_write); gamma/beta/m/rs staged in LDS once per block.
// ---------------------------------------------------------------------------
__global__ __launch_bounds__(256)
void proj_kernel(const __bf16* __restrict__ ANQ, const __bf16* __restrict__ WQT,
                 const float* __restrict__ ctx, const __bf16* __restrict__ WKT,
                 const float* __restrict__ kvg, const float* __restrict__ kvb,
                 const float* __restrict__ MRS, const __bf16* __restrict__ WVPT,
                 float* __restrict__ qsl, __bf16* __restrict__ kout,
                 float* __restrict__ vpm) {
    __shared__ __align__(16) __bf16 As[128 * 32];
    __shared__ __align__(16) __bf16 Bs[128 * 32];
    __shared__ __align__(16) float gsh[1024];
    __shared__ __align__(16) float bsh[1024];
    __shared__ float msh[128], rsh[128];
    int b = blockIdx.x;
    int tid = threadIdx.x;
    int lane = tid & 63, w = tid >> 6;
    int n16 = lane & 15, quad = lane >> 4;
    int wr = (w >> 1) * 64, wc = (w & 1) * 64;

    const __bf16 *B;
    int K, kbeg, kend, mode, slice = 0;
    long long m0, n0;
    const __bf16* aGq = nullptr;
    if (b < 224) {
        mode = 0; slice = b / 28;
        int rem = b % 28;
        m0 = (long long)(rem % 7) * 128;
        n0 = (long long)(rem / 7) * 128;
        K = DH; kbeg = slice * 384; kend = kbeg + 384;
        B = WQT;
        aGq = ANQ + (m0 + (tid >> 2)) * K + (tid & 3) * 8;
    } else {
        mode = 1;
        int b2 = b - 224;
        m0 = (long long)(b2 & 63) * 128;
        n0 = (long long)(b2 >> 6) * 128;
        K = DC; kbeg = 0; kend = DC;
        B = WKT;
        // stage gamma/beta + m/rs for this m-panel
        for (int i = tid; i < 256; i += 256) {
            ((f32x4*)gsh)[i] = ((const f32x4*)kvg)[i];
            ((f32x4*)bsh)[i] = ((const f32x4*)kvb)[i];
        }
        if (tid < 128) {
            long long gr = m0 + tid; if (gr >= MKV) gr = MKV - 1;
            msh[tid] = MRS[gr * 2];
            rsh[tid] = MRS[gr * 2 + 1];
        }
        __syncthreads();
    }
    bool dovp = (mode == 1) && (n0 == 0);

    const __bf16* bG = B + (n0 + (tid >> 2)) * K + (tid & 3) * 8;
    __bf16* aL = As + tid * 8;
    __bf16* bL = Bs + tid * 8;

    // k-mode A-staging source rows (clamped for pad rows; output discarded)
    int ri = tid >> 2, c8 = (tid & 3) * 8;
    long long r0c = m0 + ri;       if (r0c >= MKV) r0c = MKV - 1;
    long long r1c = m0 + 64 + ri;  if (r1c >= MKV) r1c = MKV - 1;
    const float* x0 = ctx + r0c * DC + c8;
    const float* x1 = ctx + r1c * DC + c8;
    float mv0 = msh[ri], rv0 = rsh[ri];
    float mv1 = msh[64 + ri], rv1 = rsh[64 + ri];

    f32x4 acc[4][4], accv[4];
    const f32x4 z = {0.f, 0.f, 0.f, 0.f};
    #pragma unroll
    for (int i = 0; i < 4; ++i) {
        accv[i] = z;
        #pragma unroll
        for (int j = 0; j < 4; ++j) acc[i][j] = z;
    }

    for (int k0 = kbeg; k0 < kend; k0 += 32) {
        if (mode == 0) {
            async_copy16(aGq + k0, aL);
            async_copy16(aGq + (long long)64 * K + k0, aL + 2048);
        } else {
            // in-staging LayerNorm: (x - m) * rs * g + b -> bf16 -> LDS
            f32x4 a0 = *(const f32x4*)(x0 + k0);
            f32x4 a1 = *(const f32x4*)(x0 + k0 + 4);
            f32x4 c0 = *(const f32x4*)(x1 + k0);
            f32x4 c1 = *(const f32x4*)(x1 + k0 + 4);
            const float* gp = &gsh[k0 + c8];
            const float* bp = &bsh[k0 + c8];
            __bf16 o0[8], o1[8];
            #pragma unroll
            for (int j = 0; j < 4; ++j) {
                o0[j]     = (__bf16)((a0[j] - mv0) * rv0 * gp[j]     + bp[j]);
                o0[j + 4] = (__bf16)((a1[j] - mv0) * rv0 * gp[j + 4] + bp[j + 4]);
                o1[j]     = (__bf16)((c0[j] - mv1) * rv1 * gp[j]     + bp[j]);
                o1[j + 4] = (__bf16)((c1[j] - mv1) * rv1 * gp[j + 4] + bp[j + 4]);
            }
            *(bf16x8*)aL = *(bf16x8*)o0;
            *(bf16x8*)(aL + 2048) = *(bf16x8*)o1;
        }
        async_copy16(bG + k0, bL);
        async_copy16(bG + (long long)64 * K + k0, bL + 2048);
        bf16x8 bv;
        if (dovp) bv = *(const bf16x8*)&WVPT[n16 * 1024 + k0 + quad * 8];
        __syncthreads();
        bf16x8 af[4], bfr[4];
        #pragma unroll
        for (int i = 0; i < 4; ++i)
            af[i]  = *(const bf16x8*)&As[(wr + i * 16 + n16) * 32 + quad * 8];
        #pragma unroll
        for (int j = 0; j < 4; ++j)
            bfr[j] = *(const bf16x8*)&Bs[(wc + j * 16 + n16) * 32 + quad * 8];
        #pragma unroll
        for (int i = 0; i < 4; ++i)
            #pragma unroll
            for (int j = 0; j < 4; ++j)
                acc[i][j] = __builtin_amdgcn_mfma_f32_16x16x32_bf16(af[i], bfr[j], acc[i][j], 0, 0, 0);
        if (dovp) {
            #pragma unroll
            for (int i = 0; i < 4; ++i)
                accv[i] = __builtin_amdgcn_mfma_f32_16x16x32_bf16(af[i], bv, accv[i], 0, 0, 0);
        }
        __syncthreads();
    }

    if (mode == 0) {
        float* qdst = qsl + (long long)slice * (N_SEQ * INNER);
        #pragma unroll
        for (int i = 0; i < 4; ++i)
            #pragma unroll
            for (int r = 0; r < 4; ++r) {
                long long gr = m0 + wr + i * 16 + quad * 4 + r;
                #pragma unroll
                for (int j = 0; j < 4; ++j) {
                    long long gc = n0 + wc + j * 16 + n16;
                    qdst[gr * INNER + gc] = acc[i][j][r];
                }
            }
    } else {
        #pragma unroll
        for (int i = 0; i < 4; ++i)
            #pragma unroll
            for (int r = 0; r < 4; ++r) {
                long long gr = m0 + wr + i * 16 + quad * 4 + r;
                if (gr >= MKV) continue;
                int cc = (int)(gr / JLEN), jj = (int)(gr % JLEN);
                #pragma unroll
                for (int j = 0; j < 4; ++j) {
                    long long gc = n0 + wc + j * 16 + n16;
                    kout[((long long)(cc * 128) + jj + 1) * INNER + gc] = (__bf16)acc[i][j][r];
                }
                if (dovp && n16 < 8) vpm[gr * 8 + n16] = accv[i][r];
            }
    }
}

// ---------------------------------------------------------------------------
// K3: reduce 8 q split-K slices -> bf16 (float4-vectorized, 448 blocks)
// ---------------------------------------------------------------------------
__global__ __launch_bounds__(256)
void qreduce_kernel(const float* __restrict__ qsl, __bf16* __restrict__ qbf) {
    int i = blockIdx.x * 256 + threadIdx.x;   // 0..114687 float4 groups
    float4 s4 = {0.f, 0.f, 0.f, 0.f};
    #pragma unroll
    for (int k = 0; k < 8; ++k) {
        float4 a = *(const float4*)&qsl[(long long)k * (N_SEQ * INNER) + i * 4];
        s4.x += a.x; s4.y += a.y; s4.z += a.z; s4.w += a.w;
    }
    __bf16 ov[4] = {(__bf16)s4.x, (__bf16)s4.y, (__bf16)s4.z, (__bf16)s4.w};
    *(ushort4*)&qbf[i * 4] = *(ushort4*)ov;
}

// ---------------------------------------------------------------------------
// K4: attention via MFMA. 512 blocks; K/vp/mask staged ONCE, loop 7 q-tiles.
// + T5 setprio around the MFMA cluster (independent-block regime, m191).
// ---------------------------------------------------------------------------
#define KROW 72   // LDS row stride in bf16 (64 data + 8 pad)

__global__ __launch_bounds__(256)
void attn_mfma_kernel(const __bf16* __restrict__ qb, const __bf16* __restrict__ kb,
                      const float* __restrict__ vpm, const float* __restrict__ vpnull,
                      const int* __restrict__ mask, float* __restrict__ s_buf) {
    __shared__ __align__(16) __bf16 ksh[128 * KROW];
    __shared__ float vpsh[128];
    __shared__ float amsh[128];
    int ch = blockIdx.x;
    int h = ch & 7, c = ch >> 3;
    int tid = threadIdx.x;
    int lane = tid & 63, w = tid >> 6;
    int n16 = lane & 15, quad = lane >> 4;

    const __bf16* kbase = kb + (long long)(c * 128) * INNER + h * DHEAD;
    #pragma unroll
    for (int p = 0; p < 4; ++p) {
        int chunk = tid + p * 256;          // 0..1023
        int row = chunk >> 3, o = chunk & 7;
        bf16x8 v = *(const bf16x8*)(kbase + (long long)row * INNER + o * 8);
        *(bf16x8*)&ksh[row * KROW + o * 8] = v;
    }
    if (tid < 128) {
        vpsh[tid] = (tid == 0) ? vpnull[h] : vpm[(long long)(c * JLEN + tid - 1) * 8 + h];
        amsh[tid] = (tid == 0) ? 0.f : (mask[tid - 1] ? 0.f : -3.0e38f);
    }
    __syncthreads();

    bf16x8 bF[8][2];
    #pragma unroll
    for (int t = 0; t < 8; ++t)
        #pragma unroll
        for (int s = 0; s < 2; ++s)
            bF[t][s] = *(const bf16x8*)&ksh[(t * 16 + n16) * KROW + s * 32 + quad * 8];

    float vpv[8], am[8];
    #pragma unroll
    for (int t = 0; t < 8; ++t) {
        vpv[t] = vpsh[t * 16 + n16];
        am[t]  = amsh[t * 16 + n16];
    }

    const __bf16* qbase = qb + h * DHEAD;
    const f32x4 zero = {0.f, 0.f, 0.f, 0.f};

    for (int xi = 0; xi < 7; ++xi) {
        bf16x8 aF[2][2];
        int r0s[2];
        #pragma unroll
        for (int it2 = 0; it2 < 2; ++it2) {
            int tile = xi * 8 + it2 * 4 + w;   // 0..55
            r0s[it2] = tile * 16;
            const __bf16* qrow = qbase + (long long)(r0s[it2] + n16) * INNER + quad * 8;
            aF[it2][0] = *(const bf16x8*)(qrow);
            aF[it2][1] = *(const bf16x8*)(qrow + 32);
        }

        #pragma unroll
        for (int it2 = 0; it2 < 2; ++it2) {
            int r0 = r0s[it2];
            f32x4 acc[8];
            __builtin_amdgcn_s_setprio(1);
            #pragma unroll
            for (int t = 0; t < 8; ++t) {
                acc[t] = __builtin_amdgcn_mfma_f32_16x16x32_bf16(aF[it2][0], bF[t][0], zero,   0, 0, 0);
                acc[t] = __builtin_amdgcn_mfma_f32_16x16x32_bf16(aF[it2][1], bF[t][1], acc[t], 0, 0, 0);
            }
            __builtin_amdgcn_s_setprio(0);
            float mloc = -3.0e38f;
            #pragma unroll
            for (int t = 0; t < 8; ++t)
                #pragma unroll
                for (int r = 0; r < 4; ++r)
                    mloc = fmaxf(mloc, acc[t][r] * 0.125f + am[t]);
            #pragma unroll
            for (int o = 1; o < 16; o <<= 1) mloc = fmaxf(mloc, __shfl_xor(mloc, o, 16));
            float lr[4] = {0.f, 0.f, 0.f, 0.f}, pr[4] = {0.f, 0.f, 0.f, 0.f};
            #pragma unroll
            for (int t = 0; t < 8; ++t) {
                #pragma unroll
                for (int r = 0; r < 4; ++r) {
                    float e = __expf(acc[t][r] * 0.125f + am[t] - mloc);
                    lr[r] += e; pr[r] += e * vpv[t];
                }
            }
            #pragma unroll
            for (int o = 1; o < 16; o <<= 1) {
                #pragma unroll
                for (int r = 0; r < 4; ++r) {
                    lr[r] += __shfl_xor(lr[r], o, 16);
                    pr[r] += __shfl_xor(pr[r], o, 16);
                }
            }
            if (n16 == 0) {
                #pragma unroll
                for (int r = 0; r < 4; ++r)
                    s_buf[(long long)ch * N_SEQ + r0 + quad * 4 + r] = pr[r] / lr[r];
            }
        }
    }
}

// ---------------------------------------------------------------------------
// K5: final: pred[n,c] = softplus(e_dot[n] + sum_h s[c,h,n] + bop + bp)
// ---------------------------------------------------------------------------
__global__ void final_kernel(const float* __restrict__ s_buf,
                             const float* __restrict__ e_dot,
                             const float* __restrict__ bop,
                             const float* __restrict__ bp,
                             float* __restrict__ out) {
    int t = blockIdx.x * blockDim.x + threadIdx.x;
    if (t >= N_SEQ * NCTX) return;
    int n = t >> 6, c = t & 63;
    float s = 0.f;
    #pragma unroll
    for (int h = 0; h < HEADS; ++h) s += s_buf[((long long)(c * HEADS + h)) * N_SEQ + n];
    float x = e_dot[n] + s + *bop + *bp;
    out[t] = fmaxf(x, 0.f) + log1pf(__expf(-fabsf(x)));
}

// ---------------------------------------------------------------------------
extern "C" void kernel_launch(void* const* d_in, const int* in_sizes, int n_in,
                              void* d_out, int out_size, void* d_ws, size_t ws_size,
                              hipStream_t stream) {
    const float* emb   = (const float*)d_in[0];
    const float* ctx   = (const float*)d_in[1];
    const int*   cmask = (const int*)  d_in[2];
    const float* qg    = (const float*)d_in[3];
    const float* qb_   = (const float*)d_in[4];
    const float* kvg   = (const float*)d_in[5];
    const float* kvb   = (const float*)d_in[6];
    const float* Wq    = (const float*)d_in[7];
    const float* Wkv   = (const float*)d_in[8];
    const float* nullk = (const float*)d_in[9];
    const float* nullv = (const float*)d_in[10];
    const float* Wo    = (const float*)d_in[11];
    const float* bo    = (const float*)d_in[12];
    const float* Wp    = (const float*)d_in[13];
    const float* bp    = (const float*)d_in[14];
    float* out  = (float*)d_out;
    float* ws_f = (float*)d_ws;

    float*  EDOT   = ws_f + OFF_EDOT;
    __bf16* QBF    = (__bf16*)(ws_f + OFF_QBF);
    __bf16* KBF    = (__bf16*)(ws_f + OFF_KBF);
    float*  VPM    = ws_f + OFF_VPM;
    float*  VPNULL = ws_f + OFF_VPNULL;
    float*  BOP    = ws_f + OFF_BOP;
    float*  SBUF   = ws_f + OFF_SBUF;
    __bf16* ANQ    = (__bf16*)(ws_f + OFF_ANQ);
    __bf16* WQT    = (__bf16*)(ws_f + OFF_WQT);
    __bf16* WKT    = (__bf16*)(ws_f + OFF_WKT);
    __bf16* WVPT   = (__bf16*)(ws_f + OFF_WVPT);
    float*  QSL    = ws_f + OFF_QSL;
    float*  MRS    = ws_f + OFF_MRS;

    prep_kernel<<<GRIDP, 256, 0, stream>>>(
        emb, ctx, qg, qb_, Wq, Wkv, Wo, bo, Wp, nullk, nullv,
        ANQ, MRS, WQT, WKT, WVPT, VPNULL, EDOT, BOP, KBF);
    proj_kernel<<<480, 256, 0, stream>>>(
        ANQ, WQT, ctx, WKT, kvg, kvb, MRS, WVPT, QSL, KBF, VPM);
    qreduce_kernel<<<(N_SEQ * INNER) / 1024, 256, 0, stream>>>(QSL, QBF);
    attn_mfma_kernel<<<NCTX * HEADS, 256, 0, stream>>>(
        QBF, KBF, VPM, VPNULL, cmask, SBUF);
    final_kernel<<<(N_SEQ * NCTX + 255) / 256, 256, 0, stream>>>(SBUF, EDOT, BOP, bp, out);
}

// Round 14
// 211.107 us; speedup vs baseline: 1.0853x; 1.0853x over previous
//
#include <hip/hip_runtime.h>
#include <math.h>

// ---------------------------------------------------------------------------
// Problem constants
// ---------------------------------------------------------------------------
#define N_SEQ   896
#define DH      3072
#define NCTX    64
#define JLEN    127
#define DC      1024
#define HEADS   8
#define DHEAD   64
#define INNER   512   // HEADS*DHEAD
#define MKV     8128  // NCTX*JLEN
#define MKVPAD  8192

typedef __bf16 bf16x8 __attribute__((ext_vector_type(8)));
typedef float  f32x4  __attribute__((ext_vector_type(4)));

// workspace float offsets
#define OFF_EDOT   0LL
#define OFF_QBF    (OFF_EDOT + N_SEQ)
#define OFF_KBF    (OFF_QBF  + (long long)N_SEQ*INNER/2)     // bf16 896x512
#define OFF_VPM    (OFF_KBF  + (long long)NCTX*128*INNER/2)  // fp32 8128x8
#define OFF_VPNULL (OFF_VPM  + (long long)MKV*8)
#define OFF_WOP    (OFF_VPNULL + 8)                          // (unused, layout kept)
#define OFF_BOP    (OFF_WOP  + INNER)
#define OFF_SBUF   (OFF_BOP  + 16)                           // fp32 64*8*896
#define OFF_ANQ    (OFF_SBUF + (long long)NCTX*HEADS*N_SEQ)  // bf16 896x3072
#define OFF_ANKV   (OFF_ANQ  + (long long)N_SEQ*DH/2)        // bf16 8192x1024
#define OFF_WQT    (OFF_ANKV + (long long)MKVPAD*DC/2)       // bf16 512x3072
#define OFF_WKT    (OFF_WQT  + (long long)INNER*DH/2)        // bf16 512x1024
#define OFF_WVPT   (OFF_WKT  + (long long)INNER*DC/2)        // bf16 16x1024
#define OFF_QSL    (OFF_WVPT + 16*1024/2)                    // fp32 8 x 896x512

// ---------------------------------------------------------------------------
__device__ __forceinline__ void async_copy16(const __bf16* g, __bf16* l) {
    __builtin_amdgcn_global_load_lds(
        (const __attribute__((address_space(1))) unsigned int*)g,
        (__attribute__((address_space(3))) unsigned int*)l,
        16, 0, 0);
}

// ---------------------------------------------------------------------------
// K1 prep: ALL prep in one kernel (no internal dependencies, no fences).
// Per-head blocks compute their OWN wop slice (Wp in LDS, wave-per-row).
//   blocks [0,8)        per-head: wop slice -> WVPT row + VPNULL
//   block  8            BOP = dot(bo, Wp)
//   block  9            misc: WVPT zero pad + null_k rows of KBF
//   blocks [10,2042)    kv LayerNorm, wave-per-row, nt loads (ctx read-once)
//   blocks [2042,2266)  q LayerNorm + emb.Wp dot, wave-per-row, two-pass
//   blocks [2266,4314)  32x32 transposes: Wq->WQT (1536), Wkv k-half->WKT (512)
// ---------------------------------------------------------------------------
#define P_KV0  10
#define P_Q0   (P_KV0 + 2032)   // 2042
#define P_T0   (P_Q0 + 224)     // 2266
#define GRIDP  (P_T0 + 2048)    // 4314

__global__ __launch_bounds__(256)
void prep_kernel(const float* __restrict__ emb, const float* __restrict__ ctx,
                 const float* __restrict__ qg, const float* __restrict__ qb_,
                 const float* __restrict__ kvg, const float* __restrict__ kvb,
                 const float* __restrict__ Wq, const float* __restrict__ Wkv,
                 const float* __restrict__ Wo, const float* __restrict__ bo,
                 const float* __restrict__ Wp,
                 const float* __restrict__ nullk, const float* __restrict__ nullv,
                 __bf16* __restrict__ ANQ, __bf16* __restrict__ ANKV,
                 __bf16* __restrict__ WQT, __bf16* __restrict__ WKT,
                 __bf16* __restrict__ WVPT, float* __restrict__ VPNULL,
                 float* __restrict__ EDOT, float* __restrict__ BOP,
                 __bf16* __restrict__ KBF)
{
    __shared__ __align__(16) float SM[3072 + 64];   // Wp stage + wop slice / tT alias
    const int bid = blockIdx.x, tid = threadIdx.x;
    const int lane = tid & 63, wid = tid >> 6;

    if (bid < 8) {
        // ---- per-head: self-contained wop slice -> WVPT row + VPNULL ----
        int h = bid;
        float* wpsh = SM;              // 3072 floats
        float* wops = SM + 3072;       // 64 floats
        for (int i = tid; i < 768; i += 256)
            ((f32x4*)wpsh)[i] = ((const f32x4*)Wp)[i];
        __syncthreads();
        for (int rr = 0; rr < 16; ++rr) {
            int d = wid * 16 + rr;
            const float* worow = Wo + (long long)(h * 64 + d) * DH;
            float s = 0.f;
            #pragma unroll
            for (int c = 0; c < 12; ++c) {
                int col = c * 256 + lane * 4;
                float4 a = *(const float4*)&worow[col];
                s += a.x*wpsh[col] + a.y*wpsh[col+1] + a.z*wpsh[col+2] + a.w*wpsh[col+3];
            }
            #pragma unroll
            for (int o = 1; o < 64; o <<= 1) s += __shfl_xor(s, o);
            if (lane == 0) wops[d] = s;
        }
        __syncthreads();
        if (tid < 64) {
            float v = nullv[h * 64 + tid] * wops[tid];
            #pragma unroll
            for (int o = 1; o < 64; o <<= 1) v += __shfl_xor(v, o);
            if (tid == 0) VPNULL[h] = v;
        }
        #pragma unroll
        for (int kk = 0; kk < 4; ++kk) {
            int k = kk * 256 + tid;
            const float* src = Wkv + (long long)k * (2 * INNER) + INNER + h * 64;
            float s2 = 0.f;
            #pragma unroll
            for (int d2 = 0; d2 < 64; d2 += 4) {
                float4 a = *(const float4*)&src[d2];
                s2 += a.x*wops[d2] + a.y*wops[d2+1] + a.z*wops[d2+2] + a.w*wops[d2+3];
            }
            WVPT[h * 1024 + k] = (__bf16)s2;
        }
    } else if (bid == 8) {
        // ---- BOP = dot(bo, Wp) ----
        float* red = SM;
        float s = 0.f;
        #pragma unroll
        for (int i = 0; i < 3; ++i) {
            int k = i * 1024 + tid * 4;
            float4 a = *(const float4*)&bo[k];
            float4 w = *(const float4*)&Wp[k];
            s += a.x*w.x + a.y*w.y + a.z*w.z + a.w*w.w;
        }
        #pragma unroll
        for (int o = 1; o < 64; o <<= 1) s += __shfl_xor(s, o);
        if (lane == 0) red[wid] = s;
        __syncthreads();
        if (tid == 0) *BOP = red[0] + red[1] + red[2] + red[3];
    } else if (bid == 9) {
        // ---- misc: WVPT zero pad rows 8..15 + null_k rows of KBF ----
        for (int i = tid; i < 8 * 1024; i += 256)
            WVPT[8 * 1024 + i] = (__bf16)0.f;
        for (int i = tid; i < NCTX * INNER; i += 256) {
            int c = i >> 9, d2 = i & 511;
            KBF[(long long)(c * 128) * INNER + d2] = (__bf16)nullk[d2];
        }
    } else if (bid < P_Q0) {
        // ---- kv LN: one wave per row; nt loads (ctx read exactly once) ----
        int r = (bid - P_KV0) * 4 + wid;             // 0..8127
        const float* x = ctx + (long long)r * DC;
        f32x4 xv[4];
        float s = 0.f, ss = 0.f;
        #pragma unroll
        for (int c = 0; c < 4; ++c) {
            const f32x4* p = (const f32x4*)&x[c * 256 + lane * 4];
            xv[c] = __builtin_nontemporal_load(p);
            s  += xv[c][0] + xv[c][1] + xv[c][2] + xv[c][3];
            ss += xv[c][0]*xv[c][0] + xv[c][1]*xv[c][1]
                + xv[c][2]*xv[c][2] + xv[c][3]*xv[c][3];
        }
        #pragma unroll
        for (int o = 1; o < 64; o <<= 1) { s += __shfl_xor(s, o); ss += __shfl_xor(ss, o); }
        float m  = s * (1.f / DC);
        float rs = rsqrtf(ss * (1.f / DC) - m * m + 1e-5f);
        __bf16* op = ANKV + (long long)r * DC;
        #pragma unroll
        for (int c = 0; c < 4; ++c) {
            int col = c * 256 + lane * 4;
            float4 g4 = *(const float4*)&kvg[col];
            float4 b4 = *(const float4*)&kvb[col];
            __bf16 ov[4];
            ov[0] = (__bf16)((xv[c][0] - m) * rs * g4.x + b4.x);
            ov[1] = (__bf16)((xv[c][1] - m) * rs * g4.y + b4.y);
            ov[2] = (__bf16)((xv[c][2] - m) * rs * g4.z + b4.z);
            ov[3] = (__bf16)((xv[c][3] - m) * rs * g4.w + b4.w);
            *(ushort4*)&op[col] = *(ushort4*)ov;
        }
    } else if (bid < P_T0) {
        // ---- q LN: one wave per row, two-pass (emb re-read from L2) ----
        int r = (bid - P_Q0) * 4 + wid;              // 0..895
        const float* x = emb + (long long)r * DH;
        float s = 0.f, ss = 0.f, dp = 0.f;
        #pragma unroll
        for (int c = 0; c < 12; ++c) {
            int col = c * 256 + lane * 4;
            float4 a = *(const float4*)&x[col];
            float4 w = *(const float4*)&Wp[col];
            s  += a.x + a.y + a.z + a.w;
            ss += a.x*a.x + a.y*a.y + a.z*a.z + a.w*a.w;
            dp += a.x*w.x + a.y*w.y + a.z*w.z + a.w*w.w;
        }
        #pragma unroll
        for (int o = 1; o < 64; o <<= 1) {
            s += __shfl_xor(s, o); ss += __shfl_xor(ss, o); dp += __shfl_xor(dp, o);
        }
        float m  = s * (1.f / DH);
        float rs = rsqrtf(ss * (1.f / DH) - m * m + 1e-5f);
        __bf16* op = ANQ + (long long)r * DH;
        #pragma unroll
        for (int c = 0; c < 12; ++c) {
            int col = c * 256 + lane * 4;
            float4 a  = *(const float4*)&x[col];
            float4 g4 = *(const float4*)&qg[col];
            float4 b4 = *(const float4*)&qb_[col];
            __bf16 ov[4];
            ov[0] = (__bf16)((a.x - m) * rs * g4.x + b4.x);
            ov[1] = (__bf16)((a.y - m) * rs * g4.y + b4.y);
            ov[2] = (__bf16)((a.z - m) * rs * g4.z + b4.z);
            ov[3] = (__bf16)((a.w - m) * rs * g4.w + b4.w);
            *(ushort4*)&op[col] = *(ushort4*)ov;
        }
        if (lane == 0) EDOT[r] = dp;
    } else {
        // ---- 32x32 transpose tiles ----
        int t = bid - P_T0;
        float (*tT)[33] = (float(*)[33])SM;
        const float* src; __bf16* dst; int srcS, dstS, rb, cb;
        if (t < 1536) {
            rb = (t >> 4) * 32; cb = (t & 15) * 32;
            src = Wq; srcS = INNER; dst = WQT; dstS = DH;
        } else {
            int bi = t - 1536;
            rb = (bi >> 4) * 32; cb = (bi & 15) * 32;
            src = Wkv; srcS = 2 * INNER; dst = WKT; dstS = DC;
        }
        int tx = tid & 31, ty = tid >> 5;
        #pragma unroll
        for (int i = 0; i < 32; i += 8)
            tT[ty + i][tx] = src[(long long)(rb + ty + i) * srcS + cb + tx];
        __syncthreads();
        #pragma unroll
        for (int i = 0; i < 32; i += 8)
            dst[(long long)(cb + ty + i) * dstS + rb + tx] = (__bf16)tT[tx][ty + i];
    }
}

// ---------------------------------------------------------------------------
// K2: merged projection GEMM (bf16 MFMA, 128x128 tile, BK=32, single-buffer,
// global_load_lds). 480 blocks; plain stores, NO fences/atomics.
// ---------------------------------------------------------------------------
__global__ __launch_bounds__(256)
void proj_kernel(const __bf16* __restrict__ ANQ, const __bf16* __restrict__ WQT,
                 const __bf16* __restrict__ ANKV, const __bf16* __restrict__ WKT,
                 const __bf16* __restrict__ WVPT,
                 float* __restrict__ qsl, __bf16* __restrict__ kout,
                 float* __restrict__ vpm) {
    __shared__ __align__(16) __bf16 As[128 * 32];
    __shared__ __align__(16) __bf16 Bs[128 * 32];
    int b = blockIdx.x;
    int tid = threadIdx.x;
    int lane = tid & 63, w = tid >> 6;
    int n16 = lane & 15, quad = lane >> 4;
    int wr = (w >> 1) * 64, wc = (w & 1) * 64;

    const __bf16 *A, *B;
    int K, kbeg, kend, mode, slice = 0;
    long long m0, n0;
    if (b < 224) {
        mode = 0; slice = b / 28;
        int rem = b % 28;
        m0 = (long long)(rem % 7) * 128;
        n0 = (long long)(rem / 7) * 128;
        K = DH; kbeg = slice * 384; kend = kbeg + 384;
        A = ANQ; B = WQT;
    } else {
        mode = 1;
        int b2 = b - 224;
        m0 = (long long)(b2 & 63) * 128;
        n0 = (long long)(b2 >> 6) * 128;
        K = DC; kbeg = 0; kend = DC;
        A = ANKV; B = WKT;
    }
    bool dovp = (mode == 1) && (n0 == 0);

    const __bf16* aG = A + (m0 + (tid >> 2)) * K + (tid & 3) * 8;
    const __bf16* bG = B + (n0 + (tid >> 2)) * K + (tid & 3) * 8;
    __bf16* aL = As + tid * 8;
    __bf16* bL = Bs + tid * 8;

    f32x4 acc[4][4], accv[4];
    const f32x4 z = {0.f, 0.f, 0.f, 0.f};
    #pragma unroll
    for (int i = 0; i < 4; ++i) {
        accv[i] = z;
        #pragma unroll
        for (int j = 0; j < 4; ++j) acc[i][j] = z;
    }

    for (int k0 = kbeg; k0 < kend; k0 += 32) {
        async_copy16(aG + k0, aL);
        async_copy16(aG + (long long)64 * K + k0, aL + 2048);
        async_copy16(bG + k0, bL);
        async_copy16(bG + (long long)64 * K + k0, bL + 2048);
        bf16x8 bv;
        if (dovp) bv = *(const bf16x8*)&WVPT[n16 * 1024 + k0 + quad * 8];
        __syncthreads();
        bf16x8 af[4], bfr[4];
        #pragma unroll
        for (int i = 0; i < 4; ++i)
            af[i]  = *(const bf16x8*)&As[(wr + i * 16 + n16) * 32 + quad * 8];
        #pragma unroll
        for (int j = 0; j < 4; ++j)
            bfr[j] = *(const bf16x8*)&Bs[(wc + j * 16 + n16) * 32 + quad * 8];
        #pragma unroll
        for (int i = 0; i < 4; ++i)
            #pragma unroll
            for (int j = 0; j < 4; ++j)
                acc[i][j] = __builtin_amdgcn_mfma_f32_16x16x32_bf16(af[i], bfr[j], acc[i][j], 0, 0, 0);
        if (dovp) {
            #pragma unroll
            for (int i = 0; i < 4; ++i)
                accv[i] = __builtin_amdgcn_mfma_f32_16x16x32_bf16(af[i], bv, accv[i], 0, 0, 0);
        }
        __syncthreads();
    }

    if (mode == 0) {
        float* qdst = qsl + (long long)slice * (N_SEQ * INNER);
        #pragma unroll
        for (int i = 0; i < 4; ++i)
            #pragma unroll
            for (int r = 0; r < 4; ++r) {
                long long gr = m0 + wr + i * 16 + quad * 4 + r;
                #pragma unroll
                for (int j = 0; j < 4; ++j) {
                    long long gc = n0 + wc + j * 16 + n16;
                    qdst[gr * INNER + gc] = acc[i][j][r];
                }
            }
    } else {
        #pragma unroll
        for (int i = 0; i < 4; ++i)
            #pragma unroll
            for (int r = 0; r < 4; ++r) {
                long long gr = m0 + wr + i * 16 + quad * 4 + r;
                if (gr >= MKV) continue;
                int cc = (int)(gr / JLEN), jj = (int)(gr % JLEN);
                #pragma unroll
                for (int j = 0; j < 4; ++j) {
                    long long gc = n0 + wc + j * 16 + n16;
                    kout[((long long)(cc * 128) + jj + 1) * INNER + gc] = (__bf16)acc[i][j][r];
                }
                if (dovp && n16 < 8) vpm[gr * 8 + n16] = accv[i][r];
            }
    }
}

// ---------------------------------------------------------------------------
// K3: reduce 8 q split-K slices -> bf16 (float4-vectorized, 448 blocks)
// ---------------------------------------------------------------------------
__global__ __launch_bounds__(256)
void qreduce_kernel(const float* __restrict__ qsl, __bf16* __restrict__ qbf) {
    int i = blockIdx.x * 256 + threadIdx.x;   // 0..114687 float4 groups
    float4 s4 = {0.f, 0.f, 0.f, 0.f};
    #pragma unroll
    for (int k = 0; k < 8; ++k) {
        float4 a = *(const float4*)&qsl[(long long)k * (N_SEQ * INNER) + i * 4];
        s4.x += a.x; s4.y += a.y; s4.z += a.z; s4.w += a.w;
    }
    __bf16 ov[4] = {(__bf16)s4.x, (__bf16)s4.y, (__bf16)s4.z, (__bf16)s4.w};
    *(ushort4*)&qbf[i * 4] = *(ushort4*)ov;
}

// ---------------------------------------------------------------------------
// K4: attention via MFMA. 512 blocks (one per (c,h)); K/vp/mask staged ONCE,
// loop over 7 q-block positions internally. + T5 setprio (m191 regime).
// ---------------------------------------------------------------------------
#define KROW 72   // LDS row stride in bf16 (64 data + 8 pad)

__global__ __launch_bounds__(256)
void attn_mfma_kernel(const __bf16* __restrict__ qb, const __bf16* __restrict__ kb,
                      const float* __restrict__ vpm, const float* __restrict__ vpnull,
                      const int* __restrict__ mask, float* __restrict__ s_buf) {
    __shared__ __align__(16) __bf16 ksh[128 * KROW];
    __shared__ float vpsh[128];
    __shared__ float amsh[128];
    int ch = blockIdx.x;
    int h = ch & 7, c = ch >> 3;
    int tid = threadIdx.x;
    int lane = tid & 63, w = tid >> 6;
    int n16 = lane & 15, quad = lane >> 4;

    const __bf16* kbase = kb + (long long)(c * 128) * INNER + h * DHEAD;
    #pragma unroll
    for (int p = 0; p < 4; ++p) {
        int chunk = tid + p * 256;          // 0..1023
        int row = chunk >> 3, o = chunk & 7;
        bf16x8 v = *(const bf16x8*)(kbase + (long long)row * INNER + o * 8);
        *(bf16x8*)&ksh[row * KROW + o * 8] = v;
    }
    if (tid < 128) {
        vpsh[tid] = (tid == 0) ? vpnull[h] : vpm[(long long)(c * JLEN + tid - 1) * 8 + h];
        amsh[tid] = (tid == 0) ? 0.f : (mask[tid - 1] ? 0.f : -3.0e38f);
    }
    __syncthreads();

    bf16x8 bF[8][2];
    #pragma unroll
    for (int t = 0; t < 8; ++t)
        #pragma unroll
        for (int s = 0; s < 2; ++s)
            bF[t][s] = *(const bf16x8*)&ksh[(t * 16 + n16) * KROW + s * 32 + quad * 8];

    float vpv[8], am[8];
    #pragma unroll
    for (int t = 0; t < 8; ++t) {
        vpv[t] = vpsh[t * 16 + n16];
        am[t]  = amsh[t * 16 + n16];
    }

    const __bf16* qbase = qb + h * DHEAD;
    const f32x4 zero = {0.f, 0.f, 0.f, 0.f};

    for (int xi = 0; xi < 7; ++xi) {
        bf16x8 aF[2][2];
        int r0s[2];
        #pragma unroll
        for (int it2 = 0; it2 < 2; ++it2) {
            int tile = xi * 8 + it2 * 4 + w;   // 0..55
            r0s[it2] = tile * 16;
            const __bf16* qrow = qbase + (long long)(r0s[it2] + n16) * INNER + quad * 8;
            aF[it2][0] = *(const bf16x8*)(qrow);
            aF[it2][1] = *(const bf16x8*)(qrow + 32);
        }

        #pragma unroll
        for (int it2 = 0; it2 < 2; ++it2) {
            int r0 = r0s[it2];
            f32x4 acc[8];
            __builtin_amdgcn_s_setprio(1);
            #pragma unroll
            for (int t = 0; t < 8; ++t) {
                acc[t] = __builtin_amdgcn_mfma_f32_16x16x32_bf16(aF[it2][0], bF[t][0], zero,   0, 0, 0);
                acc[t] = __builtin_amdgcn_mfma_f32_16x16x32_bf16(aF[it2][1], bF[t][1], acc[t], 0, 0, 0);
            }
            __builtin_amdgcn_s_setprio(0);
            float mloc = -3.0e38f;
            #pragma unroll
            for (int t = 0; t < 8; ++t)
                #pragma unroll
                for (int r = 0; r < 4; ++r)
                    mloc = fmaxf(mloc, acc[t][r] * 0.125f + am[t]);
            #pragma unroll
            for (int o = 1; o < 16; o <<= 1) mloc = fmaxf(mloc, __shfl_xor(mloc, o, 16));
            float lr[4] = {0.f, 0.f, 0.f, 0.f}, pr[4] = {0.f, 0.f, 0.f, 0.f};
            #pragma unroll
            for (int t = 0; t < 8; ++t) {
                #pragma unroll
                for (int r = 0; r < 4; ++r) {
                    float e = __expf(acc[t][r] * 0.125f + am[t] - mloc);
                    lr[r] += e; pr[r] += e * vpv[t];
                }
            }
            #pragma unroll
            for (int o = 1; o < 16; o <<= 1) {
                #pragma unroll
                for (int r = 0; r < 4; ++r) {
                    lr[r] += __shfl_xor(lr[r], o, 16);
                    pr[r] += __shfl_xor(pr[r], o, 16);
                }
            }
            if (n16 == 0) {
                #pragma unroll
                for (int r = 0; r < 4; ++r)
                    s_buf[(long long)ch * N_SEQ + r0 + quad * 4 + r] = pr[r] / lr[r];
            }
        }
    }
}

// ---------------------------------------------------------------------------
// K5: final: pred[n,c] = softplus(e_dot[n] + sum_h s[c,h,n] + bop + bp)
// ---------------------------------------------------------------------------
__global__ void final_kernel(const float* __restrict__ s_buf,
                             const float* __restrict__ e_dot,
                             const float* __restrict__ bop,
                             const float* __restrict__ bp,
                             float* __restrict__ out) {
    int t = blockIdx.x * blockDim.x + threadIdx.x;
    if (t >= N_SEQ * NCTX) return;
    int n = t >> 6, c = t & 63;
    float s = 0.f;
    #pragma unroll
    for (int h = 0; h < HEADS; ++h) s += s_buf[((long long)(c * HEADS + h)) * N_SEQ + n];
    float x = e_dot[n] + s + *bop + *bp;
    out[t] = fmaxf(x, 0.f) + log1pf(__expf(-fabsf(x)));
}

// ---------------------------------------------------------------------------
extern "C" void kernel_launch(void* const* d_in, const int* in_sizes, int n_in,
                              void* d_out, int out_size, void* d_ws, size_t ws_size,
                              hipStream_t stream) {
    const float* emb   = (const float*)d_in[0];
    const float* ctx   = (const float*)d_in[1];
    const int*   cmask = (const int*)  d_in[2];
    const float* qg    = (const float*)d_in[3];
    const float* qb_   = (const float*)d_in[4];
    const float* kvg   = (const float*)d_in[5];
    const float* kvb   = (const float*)d_in[6];
    const float* Wq    = (const float*)d_in[7];
    const float* Wkv   = (const float*)d_in[8];
    const float* nullk = (const float*)d_in[9];
    const float* nullv = (const float*)d_in[10];
    const float* Wo    = (const float*)d_in[11];
    const float* bo    = (const float*)d_in[12];
    const float* Wp    = (const float*)d_in[13];
    const float* bp    = (const float*)d_in[14];
    float* out  = (float*)d_out;
    float* ws_f = (float*)d_ws;

    float*  EDOT   = ws_f + OFF_EDOT;
    __bf16* QBF    = (__bf16*)(ws_f + OFF_QBF);
    __bf16* KBF    = (__bf16*)(ws_f + OFF_KBF);
    float*  VPM    = ws_f + OFF_VPM;
    float*  VPNULL = ws_f + OFF_VPNULL;
    float*  BOP    = ws_f + OFF_BOP;
    float*  SBUF   = ws_f + OFF_SBUF;
    __bf16* ANQ    = (__bf16*)(ws_f + OFF_ANQ);
    __bf16* ANKV   = (__bf16*)(ws_f + OFF_ANKV);
    __bf16* WQT    = (__bf16*)(ws_f + OFF_WQT);
    __bf16* WKT    = (__bf16*)(ws_f + OFF_WKT);
    __bf16* WVPT   = (__bf16*)(ws_f + OFF_WVPT);
    float*  QSL    = ws_f + OFF_QSL;

    prep_kernel<<<GRIDP, 256, 0, stream>>>(
        emb, ctx, qg, qb_, kvg, kvb, Wq, Wkv, Wo, bo, Wp, nullk, nullv,
        ANQ, ANKV, WQT, WKT, WVPT, VPNULL, EDOT, BOP, KBF);
    proj_kernel<<<480, 256, 0, stream>>>(ANQ, WQT, ANKV, WKT, WVPT, QSL, KBF, VPM);
    qreduce_kernel<<<(N_SEQ * INNER) / 1024, 256, 0, stream>>>(QSL, QBF);
    attn_mfma_kernel<<<NCTX * HEADS, 256, 0, stream>>>(
        QBF, KBF, VPM, VPNULL, cmask, SBUF);
    final_kernel<<<(N_SEQ * NCTX + 255) / 256, 256, 0, stream>>>(SBUF, EDOT, BOP, bp, out);
}